// Round 1
// baseline (486.211 us; speedup 1.0000x reference)
//
#include <hip/hip_runtime.h>
#include <cstdint>
#include <cstddef>

// Paged GQA flash-decode attention, fp32, split-KV two-pass.
// R4: fused-kvh blocks — each block consumes FULL 4KB K/V page rows
// contiguously (fixes 512B/4KB strided DRAM access of R3). Block=(b,chunk),
// 8 waves = 8 kvh, wave-private online softmax (no cross-wave combine),
// cooperative glds staging, double-buffered, XOR-swizzled LDS granules.

#define NB 16
#define NH 32
#define HD 128
#define NT 4096
#define NKVH 8
#define NG 4
#define NSPL 64
#define TT 4
#define PART_STRIDE 4160          // 32*128 o + 32 m + 32 l
#define SCALE_F 0.08838834764831845f
#define KVROW 1024                // floats per page row (all kvh)

__device__ __forceinline__ void fence_sched() { __asm__ volatile("" ::: "memory"); }
// s_waitcnt imm: [3:0]=vmcnt lo, [6:4]=expcnt, [11:8]=lgkmcnt, [15:14]=vmcnt hi
#define WAIT_VM0() { __builtin_amdgcn_s_waitcnt(0x0F70); fence_sched(); }

__device__ __forceinline__ void glds16(const float* g, float* l) {
    __builtin_amdgcn_global_load_lds(
        (__attribute__((address_space(1))) void*)g,
        (__attribute__((address_space(3))) void*)l,
        16, 0, 0);
}

__global__ __launch_bounds__(512, 4) void attn_partial_kernel(
    const float* __restrict__ q,
    const float* __restrict__ kc,
    const float* __restrict__ vc,
    const int*   __restrict__ kv_lens,
    const int*   __restrict__ btab,
    float*       __restrict__ part)
{
    __shared__ __align__(16) float kt[2][TT][KVROW];   // 32 KB
    __shared__ __align__(16) float vt[2][TT][KVROW];   // 32 KB
    __shared__ __align__(16) float p_lds[NKVH][TT][NG];
    __shared__ float a_lds[NKVH][NG];
    // 64.6 KB -> 2 blocks/CU (16 waves/CU)

    const int bid = blockIdx.x;            // b*NSPL + c
    const int c   = bid % NSPL;
    const int b   = bid / NSPL;
    const int tid = threadIdx.x;
    const int w   = tid >> 6;              // wave == kvh
    const int lane = tid & 63;

    const int kv_len = kv_lens[b];
    const int clen = (kv_len + NSPL - 1) / NSPL;
    const int t0c  = c * clen;
    const int t1c  = min(t0c + clen, kv_len);

    float* pb = part + (size_t)bid * PART_STRIDE;

    if (t0c >= kv_len) {                   // empty chunk
        for (int i = tid; i < PART_STRIDE; i += 512)
            pb[i] = (i >= 4096 && i < 4128) ? -1e30f : 0.0f;
        return;
    }

    // ---- QK lane roles: lane = (t:2)(g:2)(quarter:2)
    const int lt = lane >> 4;              // token in tile
    const int lg = (lane >> 2) & 3;        // g (head within group)
    const int lq = lane & 3;               // 32-float quarter of D

    // ---- staging roles: wave w stages row trow, 1KB chunks qb,qb+1 (K and V)
    const int trow = w >> 1;
    const int qb   = (w & 1) << 1;
    // granule swizzle (involution): S = G ^ ((t&3) | ((bit3(G))<<2))
    const int mS  = (trow & 3) | (((lane >> 3) & 1) << 2);
    const int lsw = ((lane ^ mS) << 2);    // per-lane swizzled float offset in 1KB chunk

    // q fragment: head (b, w*4+lg), quarter lq, pre-scaled. 8 float4 = 32 VGPR.
    float4 qreg[8];
    {
        const float* qp = q + ((size_t)(b * NH + w * NG + lg)) * HD + (lq << 5);
        #pragma unroll
        for (int i = 0; i < 8; ++i) {
            float4 t = *((const float4*)qp + i);
            qreg[i] = make_float4(t.x * SCALE_F, t.y * SCALE_F,
                                  t.z * SCALE_F, t.w * SCALE_F);
        }
    }

    const int* bt_b = btab + b * NT;

    // QK read swizzle mask: granule G = w*32+lq*8+i has bit3 = lq&1
    const int mR = lt | ((lq & 1) << 2);
    const float* const kqbase0 = &kt[0][lt][(w << 7) + (lq << 5)];
    const float* const kqbase1 = &kt[1][lt][(w << 7) + (lq << 5)];
    // PV per-lane base: granule bv = w*32 + lane/2 (bit3 = (lane>>4)&1)
    const int bv  = (w << 5) + (lane >> 1);
    const int vbx = ((bv ^ (((lane >> 4) & 1) << 2)) << 2) | ((lane & 1) << 1);

    float m_g = -1e30f, l_g = 0.0f;
    float o00=0,o01=0,o10=0,o11=0,o20=0,o21=0,o30=0,o31=0;

    // prologue: stage tile 0 -> buf 0 (4 glds16 per wave: 2 K + 2 V)
    {
        int tok = t0c + trow;
        int pg = bt_b[(tok < t1c) ? tok : t0c];
        const float* ks = kc + (size_t)pg * KVROW + lsw;
        const float* vs = vc + (size_t)pg * KVROW + lsw;
        fence_sched();
        glds16(ks + ((qb    ) << 8), &kt[0][trow][(qb    ) << 8]);
        glds16(ks + ((qb + 1) << 8), &kt[0][trow][(qb + 1) << 8]);
        glds16(vs + ((qb    ) << 8), &vt[0][trow][(qb    ) << 8]);
        glds16(vs + ((qb + 1) << 8), &vt[0][trow][(qb + 1) << 8]);
        fence_sched();
    }

    int bb = 0;
    for (int tcur = t0c; tcur < t1c; tcur += TT, bb ^= 1) {
        const bool has_next = (tcur + TT) < t1c;
        int pgn = 0;
        if (has_next) {
            int tok = tcur + TT + trow;
            pgn = bt_b[(tok < t1c) ? tok : t0c];   // drained by WAIT_VM0
        }

        WAIT_VM0();            // own tile-i loads (and btab) landed
        __syncthreads();       // all waves: tile i ready; tile i-1 reads done

        if (has_next) {        // stage tile i+1 -> other buffer (now safe)
            const int nb = bb ^ 1;
            const float* ks = kc + (size_t)pgn * KVROW + lsw;
            const float* vs = vc + (size_t)pgn * KVROW + lsw;
            fence_sched();
            glds16(ks + ((qb    ) << 8), &kt[nb][trow][(qb    ) << 8]);
            glds16(ks + ((qb + 1) << 8), &kt[nb][trow][(qb + 1) << 8]);
            glds16(vs + ((qb    ) << 8), &vt[nb][trow][(qb    ) << 8]);
            glds16(vs + ((qb + 1) << 8), &vt[nb][trow][(qb + 1) << 8]);
            fence_sched();
        }

        // ---- QK: lane dots its 32-float quarter for (token lt, head lg)
        const float* kRow = bb ? kqbase1 : kqbase0;
        float s = 0.0f;
        #pragma unroll
        for (int i = 0; i < 8; ++i) {
            float4 kk = *(const float4*)(kRow + ((i ^ mR) << 2));
            float4 qq = qreg[i];
            s = fmaf(kk.x,qq.x, fmaf(kk.y,qq.y, fmaf(kk.z,qq.z, fmaf(kk.w,qq.w, s))));
        }
        s += __shfl_xor(s, 1);
        s += __shfl_xor(s, 2);
        if (tcur + lt >= t1c) s = -1e30f;

        // online softmax per head g across the 4 tokens (lanes xor 16,32)
        float tmax = fmaxf(s, __shfl_xor(s, 16));
        tmax = fmaxf(tmax, __shfl_xor(tmax, 32));
        float m_new = fmaxf(m_g, tmax);
        float alpha = __expf(m_g - m_new);
        float p     = __expf(s - m_new);
        float tsum  = p;
        tsum += __shfl_xor(tsum, 16);
        tsum += __shfl_xor(tsum, 32);
        l_g = l_g * alpha + tsum;
        m_g = m_new;

        if (lq == 0) {
            p_lds[w][lt][lg] = p;
            if (lt == 0) a_lds[w][lg] = alpha;
        }

        // ---- PV: lane owns d-pair (2*lane); p broadcast; V read de-swizzled
        float a0 = a_lds[w][0], a1 = a_lds[w][1], a2 = a_lds[w][2], a3 = a_lds[w][3];
        o00 *= a0; o01 *= a0; o10 *= a1; o11 *= a1;
        o20 *= a2; o21 *= a2; o30 *= a3; o31 *= a3;
        const float* vbuf = bb ? &vt[1][0][0] : &vt[0][0][0];
        #pragma unroll
        for (int t = 0; t < TT; ++t) {
            float2 vv = *(const float2*)(vbuf + t * KVROW + (vbx ^ (t << 2)));
            float4 pp = *(const float4*)&p_lds[w][t][0];
            o00 = fmaf(pp.x, vv.x, o00); o01 = fmaf(pp.x, vv.y, o01);
            o10 = fmaf(pp.y, vv.x, o10); o11 = fmaf(pp.y, vv.y, o11);
            o20 = fmaf(pp.z, vv.x, o20); o21 = fmaf(pp.z, vv.y, o21);
            o30 = fmaf(pp.w, vv.x, o30); o31 = fmaf(pp.w, vv.y, o31);
        }
    }

    // epilogue: wave-private state -> part (no cross-wave combine needed)
    *(float2*)&pb[(w * NG + 0) * HD + (lane << 1)] = make_float2(o00, o01);
    *(float2*)&pb[(w * NG + 1) * HD + (lane << 1)] = make_float2(o10, o11);
    *(float2*)&pb[(w * NG + 2) * HD + (lane << 1)] = make_float2(o20, o21);
    *(float2*)&pb[(w * NG + 3) * HD + (lane << 1)] = make_float2(o30, o31);
    if (lq == 0 && lt == 0) {
        pb[4096 + w * NG + lg] = m_g;
        pb[4128 + w * NG + lg] = l_g;
    }
}

__global__ __launch_bounds__(256) void attn_combine_kernel(
    const float* __restrict__ part, float* __restrict__ out)
{
    const int bid = blockIdx.x;        // b*NKVH + kvh
    const int tid = threadIdx.x;
    const int g   = tid >> 6;
    const int d2  = (tid & 63) << 1;
    const int b   = bid / NKVH;
    const int kvh = bid % NKVH;
    const float* pb = part + (size_t)b * NSPL * PART_STRIDE;
    const int mi = 4096 + kvh * NG + g;
    const int li = 4128 + kvh * NG + g;
    const int oi = (kvh * NG + g) * HD + d2;

    float M = -1e30f;
    #pragma unroll 4
    for (int cc = 0; cc < NSPL; ++cc)
        M = fmaxf(M, pb[(size_t)cc * PART_STRIDE + mi]);
    float L = 0.0f, O0 = 0.0f, O1 = 0.0f;
    #pragma unroll 4
    for (int cc = 0; cc < NSPL; ++cc) {
        const float* pc = pb + (size_t)cc * PART_STRIDE;
        float sc = __expf(pc[mi] - M);                 // empty chunk -> 0
        L += pc[li] * sc;
        float2 o = *(const float2*)&pc[oi];
        O0 = fmaf(o.x, sc, O0); O1 = fmaf(o.y, sc, O1);
    }
    float inv = 1.0f / L;                              // chunk 0 non-empty -> L > 0
    const int h = kvh * NG + g;
    out[((size_t)b * NH + h) * HD + d2]     = O0 * inv;
    out[((size_t)b * NH + h) * HD + d2 + 1] = O1 * inv;
}

extern "C" void kernel_launch(void* const* d_in, const int* in_sizes, int n_in,
                              void* d_out, int out_size, void* d_ws, size_t ws_size,
                              hipStream_t stream)
{
    const float* q   = (const float*)d_in[0];
    const float* kc  = (const float*)d_in[1];
    const float* vc  = (const float*)d_in[2];
    const int*   kvl = (const int*)d_in[3];
    const int*   bt  = (const int*)d_in[4];
    float* part = (float*)d_ws;   // 1024 * 4160 * 4 B = 17.04 MB of ws used

    attn_partial_kernel<<<NB * NSPL, 512, 0, stream>>>(q, kc, vc, kvl, bt, part);
    attn_combine_kernel<<<NB * NKVH, 256, 0, stream>>>(part, (float*)d_out);
}